// Round 14
// baseline (121.330 us; speedup 1.0000x reference)
//
#include <hip/hip_runtime.h>
#include <math.h>

// ---------------- problem constants ----------------
#define NS 3000          // 30*100 samples
#define NF 147           // 3*7*7 encoder feats
#define ND 512
#define NSIG 49          // 7x7 shift classes
#define NSAMP 4          // samples per k_H2s block (750 blocks, measured best)
#define NHBLK 750        // 3000 / 4
#define NTB 1029         // 49 sig * 3 c * 7 cy  (k_TX T-blocks)
#define FTILE 16         // Wenc rows staged in LDS per H-phase tile

// ---------------- ws layout (float offsets) ----------------
#define OFF_FEATS  0            // 147 -> pad 160
#define OFF_T      160          // T2[sig][g][f]: 49*49*147 = 352947 -> 353107
#define OFF_G      353120       // 7203
// end < 360336 floats = 1.45 MB

// weight of upsample(+reflect,+shift): output pixel p, shift sigma
__device__ __forceinline__ void wt_compute(int sigma, int p, int& i0c, int& i1c,
                                           float& w0, float& w1) {
  int k = p + sigma - 3;
  int r = k < 0 ? -k : (k > 223 ? 446 - k : k);    // np.pad 'reflect'
  float tc = (float)(2 * r - 31) * (1.0f / 64.0f); // (r+0.5)/32 - 0.5, exact
  float fl = floorf(tc);
  int i0 = (int)fl;
  float fr = tc - fl;
  i0c = min(max(i0, 0), 6);
  i1c = min(max(i0 + 1, 0), 6);
  w0 = 1.0f - fr;
  w1 = fr;
}

// fused T2 build: blocks 0..1028 = (sig,c,cy) tiles (image band -> LDS ->
// V-slice -> T2 outputs, no global V); 1029..1175 feats; 1176 zeroes G
__global__ void __launch_bounds__(256) k_TX(const float* __restrict__ x,
                                            float* __restrict__ ws) {
  __shared__ float sImg[32 * 224];   // [yy][x0*7+cx] swizzled (conflict-free)
  __shared__ float4 sWx[224];        // [x0*7+cx] x-weights for sy
  __shared__ float4 sWy[32];         // y-weights for sx, rows cy*32..+32
  __shared__ float sV[32 * 49];      // [yy][cx*7+gx]
  __shared__ float red[4];
  int b = blockIdx.x;
  int t = threadIdx.x;
  if (b < NTB) {
    int cy = b % 7;
    int c  = (b / 7) % 3;
    int sig = b / 21;
    int sx = sig / 7, sy = sig % 7;
    const float* xc = x + (c * 224 + cy * 32) * 224;
    for (int e = t; e < 32 * 224; e += 256) {
      int yy = e / 224, col = e % 224;
      int cx = col >> 5, x0 = col & 31;
      sImg[yy * 224 + x0 * 7 + cx] = xc[yy * 224 + col];
    }
    if (t < 224) {
      int i0, i1; float w0, w1;
      wt_compute(sy, t, i0, i1, w0, w1);
      sWx[(t & 31) * 7 + (t >> 5)] =
          make_float4(w0, w1, __int_as_float(i0), __int_as_float(i1));
    }
    if (t < 32) {
      int i0, i1; float w0, w1;
      wt_compute(sx, cy * 32 + t, i0, i1, w0, w1);
      sWy[t] = make_float4(w0, w1, __int_as_float(i0), __int_as_float(i1));
    }
    __syncthreads();
    // V-phase: v[yy][cx][gx] = sum_x0 wx(cx*32+x0,gx;sy) * img[yy][cx*32+x0]
    for (int e = t; e < 32 * 49; e += 256) {
      int yy = e / 49, j = e % 49;
      int cx = j / 7, gx = j % 7;
      const float* row = sImg + yy * 224 + cx;
      float acc = 0.f;
      #pragma unroll 8
      for (int x0 = 0; x0 < 32; ++x0) {
        float4 wt = sWx[x0 * 7 + cx];
        int i0 = __float_as_int(wt.z), i1 = __float_as_int(wt.w);
        float w = (gx == i0 ? wt.x : 0.f) + (gx == i1 ? wt.y : 0.f);
        acc = fmaf(w, row[x0 * 7], acc);
      }
      sV[e] = acc;
    }
    __syncthreads();
    // T-phase: 343 outputs (g,cx)
    for (int e = t; e < 343; e += 256) {
      int g = e / 7, cx = e % 7;
      int gy = g / 7, gx = g % 7;
      float acc = 0.f;
      #pragma unroll 8
      for (int yy = 0; yy < 32; ++yy) {
        float4 wt = sWy[yy];
        int i0 = __float_as_int(wt.z), i1 = __float_as_int(wt.w);
        float w = (gy == i0 ? wt.x : 0.f) + (gy == i1 ? wt.y : 0.f);
        acc = fmaf(w, sV[yy * 49 + cx * 7 + gx], acc);
      }
      ws[OFF_T + (sig * 49 + g) * NF + c * 49 + cy * 7 + cx] = acc * (1.0f / 1024.0f);
    }
  } else if (b < NTB + NF) {
    int unit = b - NTB;
    int c = unit / 49, rem = unit % 49, cy = rem / 7, cx = rem % 7;
    float acc = 0.f;
    for (int idx = t; idx < 1024; idx += 256) {
      int yy = idx >> 5, xx = idx & 31;
      acc += x[(c * 224 + cy * 32 + yy) * 224 + cx * 32 + xx];
    }
    for (int off = 32; off; off >>= 1) acc += __shfl_down(acc, off);
    int wave = t >> 6, lane = t & 63;
    if (lane == 0) red[wave] = acc;
    __syncthreads();
    if (t == 0)
      ws[OFF_FEATS + unit] = (red[0] + red[1] + red[2] + red[3]) * (1.0f / 1024.0f);
  } else {
    for (int e = t; e < 7203; e += 256) ws[OFF_G + e] = 0.f;
  }
}

// fused: F = T2[sig]@g (LDS), h* col + H = F@Wenc one pass with Wenc staged
// in 16-row LDS tiles (bulk-coalesced loads instead of per-iter L2 latency
// chain), sims, then coalesced atomic flush into global G
__global__ void __launch_bounds__(256) k_H2s(const float* __restrict__ Wenc,
                                             const float* __restrict__ grids,
                                             const int* __restrict__ shx,
                                             const int* __restrict__ shy,
                                             float* __restrict__ ws) {
  __shared__ float sW[FTILE * ND];                // 32 KB Wenc tile
  __shared__ __align__(16) float sF[NF * NSAMP];  // [f][r], float4 per f
  __shared__ float sGr[NSAMP * 49];               // [r][g]
  __shared__ float sFeat[NF];
  __shared__ int   sSig[NSAMP];
  __shared__ float sRed[2][NSAMP][4];
  __shared__ float sRedH[4];
  __shared__ float sS[NSAMP];
  int t = threadIdx.x;
  int b = blockIdx.x;
  int i0s = b * NSAMP;
  for (int e = t; e < NSAMP * 49; e += 256) sGr[e] = grids[i0s * 49 + e];
  if (t < NSAMP) sSig[t] = shx[i0s + t] * 7 + shy[i0s + t];
  if (t < NF) sFeat[t] = ws[OFF_FEATS + t];
  __syncthreads();
  for (int idx = t; idx < NF * NSAMP; idx += 256) {
    int r = idx / NF, f = idx - r * NF;
    const float* T2 = ws + OFF_T + sSig[r] * (49 * NF) + f;
    const float* gr = sGr + r * 49;
    float acc = 0.f;
    #pragma unroll
    for (int g = 0; g < 49; ++g) acc = fmaf(T2[g * NF], gr[g], acc);
    sF[f * NSAMP + r] = acc;
  }
  float accA[NSAMP], accB[NSAMP];
  #pragma unroll
  for (int r = 0; r < NSAMP; ++r) { accA[r] = 0.f; accB[r] = 0.f; }
  float h0 = 0.f, h1 = 0.f;
  const float4* sF4 = (const float4*)sF;
  for (int f0 = 0; f0 < NF; f0 += FTILE) {
    int nf = min(FTILE, NF - f0);
    __syncthreads();   // sF ready (1st iter) / previous tile fully consumed
    for (int e = t; e < nf * ND; e += 256) sW[e] = Wenc[f0 * ND + e];
    __syncthreads();
    #pragma unroll 4
    for (int fr = 0; fr < nf; ++fr) {
      int f = f0 + fr;
      float w0 = sW[fr * ND + t];
      float w1 = sW[fr * ND + t + 256];
      float fe = sFeat[f];
      h0 = fmaf(fe, w0, h0);
      h1 = fmaf(fe, w1, h1);
      float4 a4 = sF4[f];
      float a[NSAMP] = {a4.x, a4.y, a4.z, a4.w};
      #pragma unroll
      for (int r = 0; r < NSAMP; ++r) {
        accA[r] = fmaf(a[r], w0, accA[r]);
        accB[r] = fmaf(a[r], w1, accB[r]);
      }
    }
  }
  int wave = t >> 6, lane = t & 63;
  float hq = h0 * h0 + h1 * h1;
  for (int off = 32; off; off >>= 1) hq += __shfl_down(hq, off);
  if (lane == 0) sRedH[wave] = hq;
  #pragma unroll
  for (int r = 0; r < NSAMP; ++r) {
    float np = accA[r] * h0 + accB[r] * h1;
    float sp = accA[r] * accA[r] + accB[r] * accB[r];
    for (int off = 32; off; off >>= 1) {
      np += __shfl_down(np, off);
      sp += __shfl_down(sp, off);
    }
    if (lane == 0) { sRed[0][r][wave] = np; sRed[1][r][wave] = sp; }
  }
  __syncthreads();
  if (t == 0) sRedH[0] = sqrtf(sRedH[0] + sRedH[1] + sRedH[2] + sRedH[3]);
  __syncthreads();
  if (t < NSAMP) {
    float np = sRed[0][t][0] + sRed[0][t][1] + sRed[0][t][2] + sRed[0][t][3];
    float sp = sRed[1][t][0] + sRed[1][t][1] + sRed[1][t][2] + sRed[1][t][3];
    float den = fmaxf(sRedH[0] * sqrtf(sp), 1e-8f);
    sS[t] = np / den;
  }
  __syncthreads();
  // flush this block's samples into G; k-fastest lanes -> coalesced runs
  for (int e = t; e < NSAMP * 3 * 49; e += 256) {
    int k = e % 49;
    int rp = e / 49;
    int r = rp / 3, p = rp - r * 3;
    float gv = sGr[r * 49 + k];
    if (gv != 0.f) {
      float s = sS[r];
      float add = (p == 0) ? 1.f : ((p == 1) ? s : s * s);
      atomicAdd(&ws[OFF_G + p * 2401 + sSig[r] * 49 + k], add);
    }
  }
}

// per-px-column C slice + final Welford output (one block per px), inline wt
__global__ void __launch_bounds__(256) k_CO(const float* __restrict__ ws,
                                            float* __restrict__ out) {
  __shared__ float Gl[3 * 2401];
  __shared__ float sC[NF];          // [k][sx][gy]
  int b = blockIdx.x;               // px
  int t = threadIdx.x;
  for (int e = t; e < 3 * 2401; e += 256) Gl[e] = ws[OFF_G + e];
  __syncthreads();
  if (t < NF) {
    int k = t / 49, r = t - k * 49;
    int sx = r / 7, gy = r % 7;
    float acc = 0.f;
    for (int sy = 0; sy < 7; ++sy) {
      int i0, i1; float w0, w1;
      wt_compute(sy, b, i0, i1, w0, w1);
      int base = k * 2401 + (sx * 7 + sy) * 49 + gy * 7;
      acc += w0 * Gl[base + i0] + w1 * Gl[base + i1];
    }
    sC[t] = acc;
  }
  __syncthreads();
  if (t < 224) {
    int py = t;
    float S0 = 0.f, S1 = 0.f, S2 = 0.f;
    for (int sx = 0; sx < 7; ++sx) {
      int i0, i1; float w0, w1;
      wt_compute(sx, py, i0, i1, w0, w1);
      int base = sx * 7;
      S0 += w0 * sC[base + i0]      + w1 * sC[base + i1];
      S1 += w0 * sC[49 + base + i0] + w1 * sC[49 + base + i1];
      S2 += w0 * sC[98 + base + i0] + w1 * sC[98 + base + i1];
    }
    float W = 1e-10f + S0;
    float R = S1 / W;
    float U = S2 - S1 * S1 / W;
    out[py * 224 + b] = R;
    out[224 * 224 + py * 224 + b] = U / (W - 1.0f);
  }
}

extern "C" void kernel_launch(void* const* d_in, const int* in_sizes, int n_in,
                              void* d_out, int out_size, void* d_ws, size_t ws_size,
                              hipStream_t stream) {
  const float* x     = (const float*)d_in[0];
  const float* Wenc  = (const float*)d_in[1];
  const float* grids = (const float*)d_in[2];
  const int*   shx   = (const int*)d_in[3];
  const int*   shy   = (const int*)d_in[4];
  float* out = (float*)d_out;
  float* ws  = (float*)d_ws;

  k_TX<<<NTB + NF + 1, 256, 0, stream>>>(x, ws);          // 1177 blocks
  k_H2s<<<NHBLK, 256, 0, stream>>>(Wenc, grids, shx, shy, ws);
  k_CO<<<224, 256, 0, stream>>>(ws, out);
}

// Round 15
// 109.919 us; speedup vs baseline: 1.1038x; 1.1038x over previous
//
#include <hip/hip_runtime.h>
#include <math.h>

// ---------------- problem constants ----------------
#define NS 3000          // 30*100 samples
#define NF 147           // 3*7*7 encoder feats
#define ND 512
#define NSIG 49          // 7x7 shift classes
#define NSAMP 4          // samples per k_H2s block (750 blocks, measured best)
#define NHBLK 750        // 3000 / 4
#define NTB 1029         // 49 sig * 3 c * 7 cy  (k_TX T-blocks)

// ---------------- ws layout (float offsets) ----------------
#define OFF_FEATS  0            // 147 -> pad 160
#define OFF_T      160          // T2[sig][g][f]: 49*49*147 = 352947 -> 353107
#define OFF_G      353120      // 7203
// end < 360336 floats = 1.45 MB

// weight of upsample(+reflect,+shift): output pixel p, shift sigma
__device__ __forceinline__ void wt_compute(int sigma, int p, int& i0c, int& i1c,
                                           float& w0, float& w1) {
  int k = p + sigma - 3;
  int r = k < 0 ? -k : (k > 223 ? 446 - k : k);    // np.pad 'reflect'
  float tc = (float)(2 * r - 31) * (1.0f / 64.0f); // (r+0.5)/32 - 0.5, exact
  float fl = floorf(tc);
  int i0 = (int)fl;
  float fr = tc - fl;
  i0c = min(max(i0, 0), 6);
  i1c = min(max(i0 + 1, 0), 6);
  w0 = 1.0f - fr;
  w1 = fr;
}

// fused T2 build: blocks 0..1028 = (sig,c,cy) tiles (image band -> LDS ->
// V-slice -> T2 outputs, no global V); 1029..1175 feats; 1176 zeroes G
__global__ void __launch_bounds__(256) k_TX(const float* __restrict__ x,
                                            float* __restrict__ ws) {
  __shared__ float sImg[32 * 224];   // [yy][x0*7+cx] swizzled (conflict-free)
  __shared__ float4 sWx[224];        // [x0*7+cx] x-weights for sy
  __shared__ float4 sWy[32];         // y-weights for sx, rows cy*32..+32
  __shared__ float sV[32 * 49];      // [yy][cx*7+gx]
  __shared__ float red[4];
  int b = blockIdx.x;
  int t = threadIdx.x;
  if (b < NTB) {
    int cy = b % 7;
    int c  = (b / 7) % 3;
    int sig = b / 21;
    int sx = sig / 7, sy = sig % 7;
    const float* xc = x + (c * 224 + cy * 32) * 224;
    for (int e = t; e < 32 * 224; e += 256) {
      int yy = e / 224, col = e % 224;
      int cx = col >> 5, x0 = col & 31;
      sImg[yy * 224 + x0 * 7 + cx] = xc[yy * 224 + col];
    }
    if (t < 224) {
      int i0, i1; float w0, w1;
      wt_compute(sy, t, i0, i1, w0, w1);
      sWx[(t & 31) * 7 + (t >> 5)] =
          make_float4(w0, w1, __int_as_float(i0), __int_as_float(i1));
    }
    if (t < 32) {
      int i0, i1; float w0, w1;
      wt_compute(sx, cy * 32 + t, i0, i1, w0, w1);
      sWy[t] = make_float4(w0, w1, __int_as_float(i0), __int_as_float(i1));
    }
    __syncthreads();
    // V-phase: v[yy][cx][gx] = sum_x0 wx(cx*32+x0,gx;sy) * img[yy][cx*32+x0]
    for (int e = t; e < 32 * 49; e += 256) {
      int yy = e / 49, j = e % 49;
      int cx = j / 7, gx = j % 7;
      const float* row = sImg + yy * 224 + cx;
      float acc = 0.f;
      #pragma unroll 8
      for (int x0 = 0; x0 < 32; ++x0) {
        float4 wt = sWx[x0 * 7 + cx];
        int i0 = __float_as_int(wt.z), i1 = __float_as_int(wt.w);
        float w = (gx == i0 ? wt.x : 0.f) + (gx == i1 ? wt.y : 0.f);
        acc = fmaf(w, row[x0 * 7], acc);
      }
      sV[e] = acc;
    }
    __syncthreads();
    // T-phase: 343 outputs (g,cx)
    for (int e = t; e < 343; e += 256) {
      int g = e / 7, cx = e % 7;
      int gy = g / 7, gx = g % 7;
      float acc = 0.f;
      #pragma unroll 8
      for (int yy = 0; yy < 32; ++yy) {
        float4 wt = sWy[yy];
        int i0 = __float_as_int(wt.z), i1 = __float_as_int(wt.w);
        float w = (gy == i0 ? wt.x : 0.f) + (gy == i1 ? wt.y : 0.f);
        acc = fmaf(w, sV[yy * 49 + cx * 7 + gx], acc);
      }
      ws[OFF_T + (sig * 49 + g) * NF + c * 49 + cy * 7 + cx] = acc * (1.0f / 1024.0f);
    }
  } else if (b < NTB + NF) {
    int unit = b - NTB;
    int c = unit / 49, rem = unit % 49, cy = rem / 7, cx = rem % 7;
    float acc = 0.f;
    for (int idx = t; idx < 1024; idx += 256) {
      int yy = idx >> 5, xx = idx & 31;
      acc += x[(c * 224 + cy * 32 + yy) * 224 + cx * 32 + xx];
    }
    for (int off = 32; off; off >>= 1) acc += __shfl_down(acc, off);
    int wave = t >> 6, lane = t & 63;
    if (lane == 0) red[wave] = acc;
    __syncthreads();
    if (t == 0)
      ws[OFF_FEATS + unit] = (red[0] + red[1] + red[2] + red[3]) * (1.0f / 1024.0f);
  } else {
    for (int e = t; e < 7203; e += 256) ws[OFF_G + e] = 0.f;
  }
}

// fused: F = T2[sig]@g (LDS), h* col + H = F@Wenc one pass, s_i in LDS,
// then per-sample coalesced atomic flush into global G (k-fastest lanes)
// R10/R12-measured best form: 256 threads, 2 d-cols/thread, NSAMP=4
__global__ void __launch_bounds__(256) k_H2s(const float* __restrict__ Wenc,
                                             const float* __restrict__ grids,
                                             const int* __restrict__ shx,
                                             const int* __restrict__ shy,
                                             float* __restrict__ ws) {
  __shared__ __align__(16) float sF[NF * NSAMP];  // [f][r], float4 per f
  __shared__ float sGr[NSAMP * 49];               // [r][g]
  __shared__ float sFeat[NF];
  __shared__ int   sSig[NSAMP];
  __shared__ float sRed[2][NSAMP][4];
  __shared__ float sRedH[4];
  __shared__ float sS[NSAMP];
  int t = threadIdx.x;
  int b = blockIdx.x;
  int i0s = b * NSAMP;
  for (int e = t; e < NSAMP * 49; e += 256) sGr[e] = grids[i0s * 49 + e];
  if (t < NSAMP) sSig[t] = shx[i0s + t] * 7 + shy[i0s + t];
  if (t < NF) sFeat[t] = ws[OFF_FEATS + t];
  __syncthreads();
  for (int idx = t; idx < NF * NSAMP; idx += 256) {
    int r = idx / NF, f = idx - r * NF;
    const float* T2 = ws + OFF_T + sSig[r] * (49 * NF) + f;
    const float* gr = sGr + r * 49;
    float acc = 0.f;
    #pragma unroll
    for (int g = 0; g < 49; ++g) acc = fmaf(T2[g * NF], gr[g], acc);
    sF[f * NSAMP + r] = acc;
  }
  __syncthreads();
  float accA[NSAMP], accB[NSAMP];
  #pragma unroll
  for (int r = 0; r < NSAMP; ++r) { accA[r] = 0.f; accB[r] = 0.f; }
  float h0 = 0.f, h1 = 0.f;
  const float* W0 = Wenc + t;
  const float* W1 = Wenc + t + 256;
  const float4* sF4 = (const float4*)sF;
  for (int f = 0; f < NF; ++f) {
    float w0 = W0[f * ND];
    float w1 = W1[f * ND];
    float fe = sFeat[f];
    h0 = fmaf(fe, w0, h0);
    h1 = fmaf(fe, w1, h1);
    float4 a4 = sF4[f];
    float a[NSAMP] = {a4.x, a4.y, a4.z, a4.w};
    #pragma unroll
    for (int r = 0; r < NSAMP; ++r) {
      accA[r] = fmaf(a[r], w0, accA[r]);
      accB[r] = fmaf(a[r], w1, accB[r]);
    }
  }
  int wave = t >> 6, lane = t & 63;
  float hq = h0 * h0 + h1 * h1;
  for (int off = 32; off; off >>= 1) hq += __shfl_down(hq, off);
  if (lane == 0) sRedH[wave] = hq;
  #pragma unroll
  for (int r = 0; r < NSAMP; ++r) {
    float np = accA[r] * h0 + accB[r] * h1;
    float sp = accA[r] * accA[r] + accB[r] * accB[r];
    for (int off = 32; off; off >>= 1) {
      np += __shfl_down(np, off);
      sp += __shfl_down(sp, off);
    }
    if (lane == 0) { sRed[0][r][wave] = np; sRed[1][r][wave] = sp; }
  }
  __syncthreads();
  if (t == 0) sRedH[0] = sqrtf(sRedH[0] + sRedH[1] + sRedH[2] + sRedH[3]);
  __syncthreads();
  if (t < NSAMP) {
    float np = sRed[0][t][0] + sRed[0][t][1] + sRed[0][t][2] + sRed[0][t][3];
    float sp = sRed[1][t][0] + sRed[1][t][1] + sRed[1][t][2] + sRed[1][t][3];
    float den = fmaxf(sRedH[0] * sqrtf(sp), 1e-8f);
    sS[t] = np / den;
  }
  __syncthreads();
  // flush this block's samples into G; k-fastest lanes -> coalesced runs
  for (int e = t; e < NSAMP * 3 * 49; e += 256) {
    int k = e % 49;
    int rp = e / 49;
    int r = rp / 3, p = rp - r * 3;
    float gv = sGr[r * 49 + k];
    if (gv != 0.f) {
      float s = sS[r];
      float add = (p == 0) ? 1.f : ((p == 1) ? s : s * s);
      atomicAdd(&ws[OFF_G + p * 2401 + sSig[r] * 49 + k], add);
    }
  }
}

// per-px-column C slice + final Welford output (one block per px), inline wt
__global__ void __launch_bounds__(256) k_CO(const float* __restrict__ ws,
                                            float* __restrict__ out) {
  __shared__ float Gl[3 * 2401];
  __shared__ float sC[NF];          // [k][sx][gy]
  int b = blockIdx.x;               // px
  int t = threadIdx.x;
  for (int e = t; e < 3 * 2401; e += 256) Gl[e] = ws[OFF_G + e];
  __syncthreads();
  if (t < NF) {
    int k = t / 49, r = t - k * 49;
    int sx = r / 7, gy = r % 7;
    float acc = 0.f;
    for (int sy = 0; sy < 7; ++sy) {
      int i0, i1; float w0, w1;
      wt_compute(sy, b, i0, i1, w0, w1);
      int base = k * 2401 + (sx * 7 + sy) * 49 + gy * 7;
      acc += w0 * Gl[base + i0] + w1 * Gl[base + i1];
    }
    sC[t] = acc;
  }
  __syncthreads();
  if (t < 224) {
    int py = t;
    float S0 = 0.f, S1 = 0.f, S2 = 0.f;
    for (int sx = 0; sx < 7; ++sx) {
      int i0, i1; float w0, w1;
      wt_compute(sx, py, i0, i1, w0, w1);
      int base = sx * 7;
      S0 += w0 * sC[base + i0]      + w1 * sC[base + i1];
      S1 += w0 * sC[49 + base + i0] + w1 * sC[49 + base + i1];
      S2 += w0 * sC[98 + base + i0] + w1 * sC[98 + base + i1];
    }
    float W = 1e-10f + S0;
    float R = S1 / W;
    float U = S2 - S1 * S1 / W;
    out[py * 224 + b] = R;
    out[224 * 224 + py * 224 + b] = U / (W - 1.0f);
  }
}

extern "C" void kernel_launch(void* const* d_in, const int* in_sizes, int n_in,
                              void* d_out, int out_size, void* d_ws, size_t ws_size,
                              hipStream_t stream) {
  const float* x     = (const float*)d_in[0];
  const float* Wenc  = (const float*)d_in[1];
  const float* grids = (const float*)d_in[2];
  const int*   shx   = (const int*)d_in[3];
  const int*   shy   = (const int*)d_in[4];
  float* out = (float*)d_out;
  float* ws  = (float*)d_ws;

  k_TX<<<NTB + NF + 1, 256, 0, stream>>>(x, ws);          // 1177 blocks
  k_H2s<<<NHBLK, 256, 0, stream>>>(Wenc, grids, shx, shy, ws);
  k_CO<<<224, 256, 0, stream>>>(ws, out);
}